// Round 13
// baseline (435.029 us; speedup 1.0000x reference)
//
#include <hip/hip_runtime.h>

// LSTM encoder B=1024,S=64,H=256 — v13: v12 + ACTUAL weight residency.
// v12's recur used __launch_bounds__(512,2) -> 128-VGPR cap -> the 192-VGPR
// wf[] could not be allocated; compiler re-streamed 384 KB/WG/step of Whh
// from L2 (VGPR_Count=128, 5.2us/step). Fix: __launch_bounds__(512,1) ->
// 256-VGPR budget; wf re-pinned INSIDE the loop (loop-carried liveness).
// Phase 1: xg = x@Wih^T + bias GEMM -> fp16 packed into d_out bytes.
// Phase 2: 256 WGs x 512 thr, 4 batches each, full H; Whh 6/8 in VGPR +
// 2/8 in LDS; per step MFMA(K=256) -> barrier -> cell -> overwrite d_out.

typedef __attribute__((ext_vector_type(8))) short short8;
typedef __attribute__((ext_vector_type(4))) float f32x4;
typedef unsigned long long u64;
typedef unsigned int u32;
typedef unsigned short u16;

#define B_ 1024
#define S_ 64
#define H_ 256
#define G_ 1024
#define OUTN (B_*S_*H_)    // f32 elems per output tensor
#define APR 266            // recur At pitch (u16)

__device__ __forceinline__ u16 f2bf(float f){
    u32 u = __builtin_bit_cast(u32, f);
    u = (u + 0x7fffu + ((u >> 16) & 1u)) >> 16;   // RNE
    return (u16)u;
}
__device__ __forceinline__ u16 f2h(float f){
    _Float16 h = (_Float16)f;
    return __builtin_bit_cast(u16, h);
}
__device__ __forceinline__ float h2f(u16 v){
    _Float16 h = __builtin_bit_cast(_Float16, v);
    return (float)h;
}
__device__ __forceinline__ float sigm(float v){ return 1.0f/(1.0f + __expf(-v)); }
__device__ __forceinline__ float tanh_(float v){ return 2.0f/(1.0f + __expf(-2.0f*v)) - 1.0f; }

__device__ __forceinline__ void gload_lds16(const void* g, void* l){
    __builtin_amdgcn_global_load_lds(
        (const __attribute__((address_space(1))) unsigned int*)g,
        (__attribute__((address_space(3))) unsigned int*)l, 16, 0, 0);
}
__device__ __forceinline__ void wg_barrier_lds(){
    asm volatile("s_waitcnt lgkmcnt(0)" ::: "memory");
    __builtin_amdgcn_sched_barrier(0);
    __builtin_amdgcn_s_barrier();
    __builtin_amdgcn_sched_barrier(0);
}

// ---------------- prep: weight conversion / fragment packing ----------------
__global__ __launch_bounds__(256) void prep_kernel(const float* __restrict__ Wih,
        const float* __restrict__ Whh, const float* __restrict__ bih,
        const float* __restrict__ bhh, u16* __restrict__ WhhF,
        u16* __restrict__ WihS, float* __restrict__ biasc){
    int idx = blockIdx.x*256 + threadIdx.x;          // 262144 threads
    if (idx < 262144){
        int e  = idx & 7, f = idx >> 3;
        int lane = f & 63, kf = (f >> 6) & 7, t = (f >> 9) & 7, w = f >> 12;
        int nl = lane & 15, kg = lane >> 4;
        int typ = t >> 1, half = t & 1;
        int row = typ*256 + w*32 + half*16 + nl;
        int k   = kf*32 + kg*8 + e;
        WhhF[idx] = f2bf(Whh[row*H_ + k]);
        int g2 = idx >> 8, k2 = idx & 255;
        int tn = g2 >> 7, n = g2 & 127, kb = k2 >> 6, kl = k2 & 63;
        int lb = (n*128 + kl*2) ^ ((n & 7) << 4);
        WihS[(size_t)(tn*4 + kb)*8192 + (lb >> 1)] = f2bf(Wih[g2*H_ + k2]);
    }
    if (idx < G_) biasc[idx] = bih[idx] + bhh[idx];
}

// ---------------- phase 1: xg GEMM -> fp16 into d_out ----------------
__global__ __launch_bounds__(256, 2) void gemm_kernel(const float* __restrict__ x,
        const u16* __restrict__ WihS, const float* __restrict__ biasc,
        u16* __restrict__ outu){
    __shared__ u16 As[2][128*72];
    __shared__ u16 Bs[2][128*64];

    const int tid = threadIdx.x, lane = tid & 63, w = tid >> 6;
    const int wm = w >> 1, wn = w & 1, nl = lane & 15, kg = lane >> 4;
    const int bid = blockIdx.x;
    const int m0 = (bid >> 3)*128, n0 = (bid & 7)*128;

    f32x4 acc[4][4];
    #pragma unroll
    for (int nt = 0; nt < 4; ++nt){
        float bq = biasc[n0 + wn*64 + nt*16 + nl];
        #pragma unroll
        for (int mt = 0; mt < 4; ++mt)
            acc[mt][nt] = (f32x4){bq, bq, bq, bq};
    }

    const int ar = tid >> 1, ah = tid & 1;
    f32x4 xa[8];
    {
        const float* xp = x + (size_t)(m0 + ar)*H_ + ah*32;
        #pragma unroll
        for (int q = 0; q < 8; ++q) xa[q] = *(const f32x4*)(xp + q*4);
        u16 tmp[32];
        #pragma unroll
        for (int q = 0; q < 32; ++q) tmp[q] = f2bf(xa[q>>2][q&3]);
        #pragma unroll
        for (int q = 0; q < 4; ++q)
            *(short8*)(&As[0][ar*72 + ah*32 + q*8]) = *(const short8*)(tmp + q*8);
        const char* src = (const char*)(WihS + (size_t)((bid & 7)*4 + 0)*8192);
        #pragma unroll
        for (int i = 0; i < 4; ++i){
            int off = (w*4 + i)*1024;
            gload_lds16(src + off + lane*16, (char*)&Bs[0][0] + off);
        }
    }
    __syncthreads();

    #pragma unroll 1
    for (int kb = 0; kb < 4; ++kb){
        const int buf = kb & 1;
        if (kb < 3){
            const float* xp = x + (size_t)(m0 + ar)*H_ + (kb+1)*64 + ah*32;
            #pragma unroll
            for (int q = 0; q < 8; ++q) xa[q] = *(const f32x4*)(xp + q*4);
            const char* src = (const char*)(WihS + (size_t)((bid & 7)*4 + kb + 1)*8192);
            #pragma unroll
            for (int i = 0; i < 4; ++i){
                int off = (w*4 + i)*1024;
                gload_lds16(src + off + lane*16, (char*)&Bs[buf^1][0] + off);
            }
        }
        #pragma unroll
        for (int kf = 0; kf < 2; ++kf){
            short8 av[4], bv[4];
            #pragma unroll
            for (int mt = 0; mt < 4; ++mt)
                av[mt] = *(const short8*)(&As[buf][(wm*64 + mt*16 + nl)*72 + kf*32 + kg*8]);
            #pragma unroll
            for (int nt = 0; nt < 4; ++nt){
                int nloc = wn*64 + nt*16 + nl;
                int byte = (nloc*128 + kf*64 + kg*16) ^ ((nl & 7) << 4);
                bv[nt] = *(const short8*)((const char*)&Bs[buf][0] + byte);
            }
            #pragma unroll
            for (int mt = 0; mt < 4; ++mt)
                #pragma unroll
                for (int nt = 0; nt < 4; ++nt)
                    acc[mt][nt] = __builtin_amdgcn_mfma_f32_16x16x32_bf16(
                                      av[mt], bv[nt], acc[mt][nt], 0, 0, 0);
        }
        if (kb < 3){
            u16 tmp[32];
            #pragma unroll
            for (int q = 0; q < 32; ++q) tmp[q] = f2bf(xa[q>>2][q&3]);
            #pragma unroll
            for (int q = 0; q < 4; ++q)
                *(short8*)(&As[buf^1][ar*72 + ah*32 + q*8]) = *(const short8*)(tmp + q*8);
        }
        __syncthreads();
    }

    #pragma unroll
    for (int mt = 0; mt < 4; ++mt)
        #pragma unroll
        for (int nt = 0; nt < 4; ++nt){
            int g = n0 + wn*64 + nt*16 + nl;
            size_t rb = (g < 512) ? 0 : (size_t)OUTN*2;
            size_t base = rb + (size_t)(m0 + wm*64 + mt*16 + kg*4)*512 + (g & 511);
            #pragma unroll
            for (int j = 0; j < 4; ++j)
                outu[base + (size_t)j*512] = f2h(acc[mt][nt][j]);
        }
}

// ---------------- phase 2: recurrence (256-VGPR budget!) ----------------
__global__ __launch_bounds__(512, 1) void recur_kernel(const u16* __restrict__ WhhF,
        const float* __restrict__ h0, const float* __restrict__ c0,
        float* __restrict__ out){
    __shared__ u16 WL[65536];        // 128 KB: Whh typ-3 tiles, frag-ordered
    __shared__ u16 At[16*APR];       // h tile (rows 0..3 real)
    __shared__ u16 xgl[2][4][1024];  // xg (fp16) double buffer

    const int tid = threadIdx.x, lane = tid & 63, w = tid >> 6;
    const int nl = lane & 15, kg = lane >> 4;
    const int b0 = blockIdx.x * 4;
    u16* outu = (u16*)out;

    // ---- W_hh: 6 tiles (typ 0..2) -> VGPRs (192), 2 tiles (typ 3) -> LDS ----
    short8 wf[6][8];
    #pragma unroll
    for (int t = 0; t < 6; ++t)
        #pragma unroll
        for (int kf = 0; kf < 8; ++kf)
            wf[t][kf] = *(const short8*)(WhhF + ((size_t)((w*8 + t)*8 + kf)*64 + lane)*8);
    #pragma unroll
    for (int t = 6; t < 8; ++t)
        #pragma unroll
        for (int kf = 0; kf < 8; ++kf){
            int db = ((w*2 + (t-6))*8 + kf)*1024;
            const char* src = (const char*)WhhF + ((size_t)((w*8 + t)*8 + kf)*64)*16 + lane*16;
            gload_lds16(src, (char*)WL + db);
        }

    for (int i = tid; i < 1024; i += 512){
        int j = i >> 8, d = i & 255;
        At[j*APR + d] = f2bf(h0[(size_t)(b0 + j)*H_ + d]);
    }
    for (int i = 4*APR + tid; i < 16*APR; i += 512)
        At[i] = 0;
    {
        int jb = w >> 1, rg = w & 1;
        const char* src = (const char*)outu
            + ((rg ? (size_t)OUTN*2 : 0) + ((size_t)(b0 + jb)*S_ + 0)*512)*2 + lane*16;
        gload_lds16(src, (char*)xgl + jb*2048 + rg*1024);
    }
    float c_[8], h_[8];
    #pragma unroll
    for (int j = 0; j < 4; ++j)
        #pragma unroll
        for (int hf = 0; hf < 2; ++hf)
            c_[j*2 + hf] = c0[(size_t)(b0 + j)*H_ + 32*w + 16*hf + nl];
    __syncthreads();

    #pragma unroll 1
    for (int s = 0; s < S_; ++s){
        // re-pin wf each iteration: loop-carried liveness, no remat/reload
        #pragma unroll
        for (int t = 0; t < 6; ++t)
            #pragma unroll
            for (int kf = 0; kf < 8; ++kf)
                asm volatile("" : "+v"(wf[t][kf]));

        const int buf = s & 1;
        if (s < S_-1){
            int jb = w >> 1, rg = w & 1;
            const char* src = (const char*)outu
                + ((rg ? (size_t)OUTN*2 : 0) + ((size_t)(b0 + jb)*S_ + s + 1)*512)*2 + lane*16;
            gload_lds16(src, (char*)xgl + (buf^1)*8192 + jb*2048 + rg*1024);
        }
        #pragma unroll
        for (int hf = 0; hf < 2; ++hf){
            f32x4 ac[4];
            #pragma unroll
            for (int typ = 0; typ < 4; ++typ){
                #pragma unroll
                for (int j = 0; j < 4; ++j){
                    float v = 0.0f;
                    if (kg == 0)
                        v = h2f(xgl[buf][j][typ*256 + 32*w + 16*hf + nl]);
                    ac[typ][j] = v;
                }
            }
            #pragma unroll
            for (int kf = 0; kf < 8; ++kf){
                short8 av = *(const short8*)(At + nl*APR + kf*32 + kg*8);
                short8 bl = *(const short8*)((const char*)WL + ((w*2 + hf)*8 + kf)*1024 + lane*16);
                ac[0] = __builtin_amdgcn_mfma_f32_16x16x32_bf16(av, wf[0 + hf][kf], ac[0], 0, 0, 0);
                ac[1] = __builtin_amdgcn_mfma_f32_16x16x32_bf16(av, wf[2 + hf][kf], ac[1], 0, 0, 0);
                ac[2] = __builtin_amdgcn_mfma_f32_16x16x32_bf16(av, wf[4 + hf][kf], ac[2], 0, 0, 0);
                ac[3] = __builtin_amdgcn_mfma_f32_16x16x32_bf16(av, bl,             ac[3], 0, 0, 0);
            }
            if (kg == 0){
                #pragma unroll
                for (int j = 0; j < 4; ++j){
                    float iv = ac[0][j], fv = ac[1][j], gv = ac[2][j], ov = ac[3][j];
                    int slot = j*2 + hf;
                    float cn = sigm(fv)*c_[slot] + sigm(iv)*tanh_(gv);
                    float hn = sigm(ov)*tanh_(cn);
                    c_[slot] = cn; h_[slot] = hn;
                }
            }
        }
        wg_barrier_lds();   // all MFMA ds_reads of At drain before overwrite

        if (kg == 0){
            #pragma unroll
            for (int j = 0; j < 4; ++j)
                #pragma unroll
                for (int hf = 0; hf < 2; ++hf){
                    int d = 32*w + 16*hf + nl;
                    float hn = h_[j*2 + hf];
                    At[j*APR + d] = f2bf(hn);
                    size_t o = ((size_t)(b0 + j)*S_ + s)*H_ + d;
                    out[o] = hn;
                    out[(size_t)OUTN + o] = hn;
                }
        }
        __syncthreads();
    }
}

extern "C" void kernel_launch(void* const* d_in, const int* in_sizes, int n_in,
                              void* d_out, int out_size, void* d_ws, size_t ws_size,
                              hipStream_t stream){
    const float* x   = (const float*)d_in[0];
    const float* h0  = (const float*)d_in[1];
    const float* c0  = (const float*)d_in[2];
    const float* Wih = (const float*)d_in[3];
    const float* Whh = (const float*)d_in[4];
    const float* bih = (const float*)d_in[5];
    const float* bhh = (const float*)d_in[6];

    u16*   WhhF  = (u16*)d_ws;                        // 512 KB @ 0
    u16*   WihS  = (u16*)((char*)d_ws + 0x80000);     // 512 KB
    float* biasc = (float*)((char*)d_ws + 0x100000);  // 4 KB

    prep_kernel<<<1024, 256, 0, stream>>>(Wih, Whh, bih, bhh, WhhF, WihS, biasc);
    gemm_kernel<<<4096, 256, 0, stream>>>(x, WihS, biasc, (u16*)d_out);
    recur_kernel<<<256, 512, 0, stream>>>(WhhF, h0, c0, (float*)d_out);
}